// Round 1
// baseline (619.039 us; speedup 1.0000x reference)
//
#include <hip/hip_runtime.h>
#include <cstdint>

// Problem: B=32, T=2048, D=1024.  M = B*T = 65536 tokens.
// scores[b,t] = v · relu(W_h·hidden[b] + W_e·enc[b,t] + bias); out = softmax_T(scores)
// Strategy: u = W_h·hidden + bias in fp32 (error-critical, tiny).
//           E = enc·W_e^T as bf16 MFMA GEMM (137 GFLOP), fused relu·v epilogue
//           with atomicAdd partial reduction over the N(d) dimension.

#define GLOBAL_AS __attribute__((address_space(1)))
#define LDS_AS    __attribute__((address_space(3)))

typedef __bf16 bf16x8 __attribute__((ext_vector_type(8)));
typedef float  f32x4  __attribute__((ext_vector_type(4)));

__device__ __forceinline__ unsigned int f2bf(float x) {
    // RNE float->bf16 (no NaN/Inf in this problem's data)
    unsigned int u = __builtin_bit_cast(unsigned int, x);
    u += 0x7fffu + ((u >> 16) & 1u);
    return u >> 16;
}

// ---- kernel 1: enc fp32 -> bf16, 8 elems/thread (BW-bound ~60us) ----
__global__ __launch_bounds__(256) void k_convert_enc(const float4* __restrict__ in,
                                                     uint4* __restrict__ out) {
    size_t idx = (size_t)blockIdx.x * 256 + threadIdx.x;
    float4 f0 = in[idx * 2];
    float4 f1 = in[idx * 2 + 1];
    uint4 o;
    o.x = f2bf(f0.x) | (f2bf(f0.y) << 16);
    o.y = f2bf(f0.z) | (f2bf(f0.w) << 16);
    o.z = f2bf(f1.x) | (f2bf(f1.y) << 16);
    o.w = f2bf(f1.z) | (f2bf(f1.w) << 16);
    out[idx] = o;
}

// ---- kernel 2: W_e = W[:,1024:2048] fp32 -> bf16 [1024x1024] (N x K, k contig) ----
__global__ __launch_bounds__(256) void k_convert_we(const float* __restrict__ W,
                                                    uint2* __restrict__ out) {
    int idx = blockIdx.x * 256 + threadIdx.x;  // one per 4 elements
    int i = idx * 4;
    int n = i >> 10, k = i & 1023;
    const float4 f = *(const float4*)(W + (size_t)n * 2048 + 1024 + k);
    uint2 o;
    o.x = f2bf(f.x) | (f2bf(f.y) << 16);
    o.y = f2bf(f.z) | (f2bf(f.w) << 16);
    out[idx] = o;
}

// ---- kernel 3: u[b,d] = hidden[b,:]·W[d,0:1024] + bias[d]  (fp32, 67 MFLOP) ----
__global__ __launch_bounds__(256) void k_hidden_proj(const float* __restrict__ hidden,
                                                     const float* __restrict__ W,
                                                     const float* __restrict__ bias,
                                                     float* __restrict__ u) {
    int b  = threadIdx.x & 31;   // 32 batches share one W row -> L1 broadcast
    int dd = threadIdx.x >> 5;   // 8 d per block
    int d  = blockIdx.x * 8 + dd;
    const float* wrow = W + (size_t)d * 2048;
    const float* hrow = hidden + b * 1024;
    float acc = 0.f;
    for (int k = 0; k < 1024; k += 4) {
        float4 w4 = *(const float4*)(wrow + k);
        float4 h4 = *(const float4*)(hrow + k);
        acc += w4.x * h4.x + w4.y * h4.y + w4.z * h4.z + w4.w * h4.w;
    }
    u[b * 1024 + d] = acc + bias[d];
}

// ---- kernel 4: 128x128-tile bf16 MFMA GEMM + fused relu·v partial-score epilogue ----
// A = enc_bf16 [65536,1024] row-major; Bw = W_e bf16 [1024,1024] (B^T layout, k contig)
__global__ __launch_bounds__(256) void k_gemm_score(
        const unsigned short* __restrict__ A,
        const unsigned short* __restrict__ Bw,
        const float* __restrict__ u,       // [32,1024] includes bias
        const float* __restrict__ v,       // [1024]
        float* __restrict__ scores) {      // [65536], pre-zeroed
    constexpr int K = 1024, BM = 128, BN = 128, BK = 32;
    __shared__ __align__(16) unsigned short As[BM * BK];  // 8 KB, linear (global_load_lds needs it)
    __shared__ __align__(16) unsigned short Bs[BN * BK];  // 8 KB

    const int tid  = threadIdx.x;
    const int wave = tid >> 6;
    const int lane = tid & 63;
    const int nb = blockIdx.x;      // 0..7   (n-tiles fastest -> 8 blocks share A-tile via L2/L3)
    const int mb = blockIdx.y;      // 0..511
    const int wm = wave & 1;        // waves 2x2 over the 128x128 tile
    const int wn = wave >> 1;
    const int q  = lane >> 4;       // MFMA quad
    const int cl = lane & 15;

    f32x4 acc[4][4];
    #pragma unroll
    for (int i = 0; i < 4; i++)
        #pragma unroll
        for (int j = 0; j < 4; j++)
            acc[i][j] = (f32x4){0.f, 0.f, 0.f, 0.f};

    // staging: chunk = 16 rows x 32 cols = 1 KB = one wave-level global_load_lds(16B/lane)
    const int rl  = lane >> 2;        // 0..15 row within chunk
    const int clk = (lane & 3) * 8;   // col (8 bf16 = 16 B per lane)
    const unsigned short* Abase = A  + (size_t)(mb * BM) * K;
    const unsigned short* Bbase = Bw + (size_t)(nb * BN) * K;

    for (int k0 = 0; k0 < K; k0 += BK) {
        #pragma unroll
        for (int c = 0; c < 2; c++) {
            const int chunk = wave * 2 + c;          // 0..7
            const int row   = chunk * 16 + rl;       // 0..127
            const unsigned short* ga = Abase + (size_t)row * K + k0 + clk;
            const unsigned short* gb = Bbase + (size_t)row * K + k0 + clk;
            __builtin_amdgcn_global_load_lds((GLOBAL_AS void*)(size_t)ga,
                                             (LDS_AS void*)(As + chunk * 512), 16, 0, 0);
            __builtin_amdgcn_global_load_lds((GLOBAL_AS void*)(size_t)gb,
                                             (LDS_AS void*)(Bs + chunk * 512), 16, 0, 0);
        }
        __syncthreads();  // compiler drains vmcnt before s_barrier (m97 behavior)

        bf16x8 a[4], b[4];
        #pragma unroll
        for (int i = 0; i < 4; i++)   // A-operand: m = lane&15, k = q*8 + j
            a[i] = *(const bf16x8*)(As + (wm * 64 + i * 16 + cl) * BK + q * 8);
        #pragma unroll
        for (int j = 0; j < 4; j++)   // B-operand: n = lane&15, k = q*8 + j
            b[j] = *(const bf16x8*)(Bs + (wn * 64 + j * 16 + cl) * BK + q * 8);
        #pragma unroll
        for (int i = 0; i < 4; i++)
            #pragma unroll
            for (int j = 0; j < 4; j++)
                acc[i][j] = __builtin_amdgcn_mfma_f32_16x16x32_bf16(a[i], b[j], acc[i][j], 0, 0, 0);
        __syncthreads();
    }

    // Epilogue: C/D layout col = lane&15 (n), row = q*4 + r (m).
    // score partial for row m over this block's 64 n's per wave, then atomicAdd.
    const int bidx = mb >> 4;  // 128 rows per block all in one batch (2048/128=16 mb per b)
    float vv[4], uu[4];
    #pragma unroll
    for (int j = 0; j < 4; j++) {
        int n = nb * BN + wn * 64 + j * 16 + cl;
        vv[j] = v[n];
        uu[j] = u[bidx * 1024 + n];
    }
    #pragma unroll
    for (int i = 0; i < 4; i++) {
        #pragma unroll
        for (int r = 0; r < 4; r++) {
            float s = 0.f;
            #pragma unroll
            for (int j = 0; j < 4; j++) {
                float e = acc[i][j][r] + uu[j];
                s += fmaxf(e, 0.f) * vv[j];
            }
            // reduce the 16 lanes (cl) that share row m
            s += __shfl_xor(s, 1);
            s += __shfl_xor(s, 2);
            s += __shfl_xor(s, 4);
            s += __shfl_xor(s, 8);
            if (cl == 0) {
                int m = mb * BM + wm * 64 + i * 16 + q * 4 + r;
                atomicAdd(&scores[m], s);
            }
        }
    }
}

// ---- kernel 5: softmax over T=2048 per batch ----
__global__ __launch_bounds__(256) void k_softmax(const float* __restrict__ scores,
                                                 float* __restrict__ out) {
    __shared__ float red[4];
    int b  = blockIdx.x;
    int t0 = threadIdx.x;
    int wave = threadIdx.x >> 6, lane = threadIdx.x & 63;
    const float* s = scores + b * 2048;
    float vals[8];
    float lmax = -1e30f;
    #pragma unroll
    for (int i = 0; i < 8; i++) {
        vals[i] = s[t0 + i * 256];
        lmax = fmaxf(lmax, vals[i]);
    }
    for (int o = 32; o > 0; o >>= 1) lmax = fmaxf(lmax, __shfl_xor(lmax, o));
    if (lane == 0) red[wave] = lmax;
    __syncthreads();
    float gmax = fmaxf(fmaxf(red[0], red[1]), fmaxf(red[2], red[3]));
    float lsum = 0.f;
    #pragma unroll
    for (int i = 0; i < 8; i++) {
        vals[i] = expf(vals[i] - gmax);
        lsum += vals[i];
    }
    for (int o = 32; o > 0; o >>= 1) lsum += __shfl_xor(lsum, o);
    __syncthreads();
    if (lane == 0) red[wave] = lsum;
    __syncthreads();
    float inv = 1.0f / (red[0] + red[1] + red[2] + red[3]);
    #pragma unroll
    for (int i = 0; i < 8; i++) out[b * 2048 + t0 + i * 256] = vals[i] * inv;
}

extern "C" void kernel_launch(void* const* d_in, const int* in_sizes, int n_in,
                              void* d_out, int out_size, void* d_ws, size_t ws_size,
                              hipStream_t stream) {
    const float* hidden = (const float*)d_in[0];  // [32,1024]
    const float* enc    = (const float*)d_in[1];  // [32,2048,1024]
    const float* W      = (const float*)d_in[2];  // [1024,2048]
    const float* bias   = (const float*)d_in[3];  // [1024]
    const float* v      = (const float*)d_in[4];  // [1024]
    float* out = (float*)d_out;                   // [32,1,2048] flat = 65536

    // workspace layout (needs ~130.4 MB)
    char* ws = (char*)d_ws;
    unsigned short* encb = (unsigned short*)ws;                         // 128 MB bf16
    unsigned short* Web  = (unsigned short*)(ws + 134217728);           // 2 MB bf16
    float* u      = (float*)(ws + 134217728 + 2097152);                 // 128 KB
    float* scores = (float*)(ws + 134217728 + 2097152 + 131072);        // 256 KB

    hipMemsetAsync(scores, 0, 65536 * sizeof(float), stream);
    k_convert_enc<<<32768, 256, 0, stream>>>((const float4*)enc, (uint4*)encb);
    k_convert_we<<<1024, 256, 0, stream>>>(W, (uint2*)Web);
    k_hidden_proj<<<128, 256, 0, stream>>>(hidden, W, bias, u);
    dim3 g(8, 512);
    k_gemm_score<<<g, 256, 0, stream>>>(encb, Web, u, v, scores);
    k_softmax<<<32, 256, 0, stream>>>(scores, out);
}